// Round 3
// baseline (811.930 us; speedup 1.0000x reference)
//
#include <hip/hip_runtime.h>
#include <stdint.h>

typedef short bf16x8 __attribute__((ext_vector_type(8)));
typedef float f32x4 __attribute__((ext_vector_type(4)));

#define BM 128
#define BN 128
#define BK 64

#define AS1 __attribute__((address_space(1)))
#define AS3 __attribute__((address_space(3)))

__device__ __forceinline__ ushort f2bf(float x) {
    uint32_t u = __float_as_uint(x);
    u += 0x7FFFu + ((u >> 16) & 1u);
    return (ushort)(u >> 16);
}

__device__ __forceinline__ void gload16(const void* g, void* l) {
    __builtin_amdgcn_global_load_lds((const AS1 void*)g, (AS3 void*)l, 16, 0, 0);
}

// C[M,N] = A[M,K] * B[N,K]^T, bf16 MFMA 16x16x32, 128x128 tile, 4 waves.
// Double-buffered LDS, prefetch-first loop, counted vmcnt (T3+T4):
//   stage t+1 -> buf^1; s_waitcnt vmcnt(8); s_barrier; compute buf;
//   lgkmcnt(0); s_barrier; swap.  Never vmcnt(0) mid-loop.
// MODE 0: bf16 out = acc (+bias), optional transposed copy (per-batch [col][row])
// MODE 1: scores: e=exp(tanh(acc)); write E + E^T bf16; atomic rowsum/colsum
// MODE 2: bf16 out = acc / scale[row]
// MODE 3: f32 out = acc + bias[col] + resid[row,col]
template<int MODE, bool HAS_BIAS, bool WRITE_T>
__global__ __launch_bounds__(256)
void gemm_bt(const ushort* __restrict__ Aptr_, const ushort* __restrict__ Bptr_,
             void* __restrict__ Cptr_, ushort* __restrict__ CTptr_,
             const float* __restrict__ bias, const float* __restrict__ resid_,
             float* __restrict__ rsum_, float* __restrict__ csum_,
             const float* __restrict__ scale_,
             int M, int N, int K, int lda, int ldb, int ldc,
             long sA, long sB, long sC, long sCT, long sSum,
             int ldct, int rbshift)
{
    __shared__ ushort Alds[2][BM * BK];
    __shared__ ushort Blds[2][BN * BK];

    const int z    = blockIdx.z;
    const int m0   = blockIdx.x * BM;
    const int n0   = blockIdx.y * BN;
    const int tid  = threadIdx.x;
    const int lane = tid & 63;
    const int wave = tid >> 6;
    const int wr   = wave >> 1, wc = wave & 1;
    const int g    = lane >> 4, c = lane & 15;

    const ushort* Ap = Aptr_ + z * sA;
    const ushort* Bp = Bptr_ + z * sB;

    f32x4 acc[4][4] = {};

    // staging: linear LDS dest (wave-uniform base + lane*16), XOR-swizzled
    // global source chunk; ds_read applies the same XOR -> conflict-free.
    auto stage = [&](int ktoff, int buf) {
        #pragma unroll
        for (int r = 0; r < 4; ++r) {
            const int li  = r * 256 + tid;     // 16B-chunk linear index
            const int row = li >> 3;
            const int gck = (li & 7) ^ (row & 7);
            gload16(Ap + (long)(m0 + row) * lda + ktoff + gck * 8, &Alds[buf][li * 8]);
            gload16(Bp + (long)(n0 + row) * ldb + ktoff + gck * 8, &Blds[buf][li * 8]);
        }
    };

    const int nk = K / BK;
    stage(0, 0);
    int cur = 0;
    for (int t = 0; t < nk; ++t) {
        if (t + 1 < nk) {
            stage((t + 1) * BK, cur ^ 1);
            asm volatile("s_waitcnt vmcnt(8)" ::: "memory");  // current tile landed; prefetch in flight
        } else {
            asm volatile("s_waitcnt vmcnt(0)" ::: "memory");
        }
        __builtin_amdgcn_s_barrier();

        #pragma unroll
        for (int kk = 0; kk < 2; ++kk) {
            bf16x8 af[4], bfr[4];
            #pragma unroll
            for (int mi = 0; mi < 4; ++mi) {
                const int row = wr * 64 + mi * 16 + c;
                const int ckq = (kk * 4 + g) ^ (row & 7);
                af[mi] = *(const bf16x8*)&Alds[cur][row * BK + ckq * 8];
            }
            #pragma unroll
            for (int ni = 0; ni < 4; ++ni) {
                const int row = wc * 64 + ni * 16 + c;
                const int ckq = (kk * 4 + g) ^ (row & 7);
                bfr[ni] = *(const bf16x8*)&Blds[cur][row * BK + ckq * 8];
            }
            #pragma unroll
            for (int mi = 0; mi < 4; ++mi)
                #pragma unroll
                for (int ni = 0; ni < 4; ++ni)
                    acc[mi][ni] = __builtin_amdgcn_mfma_f32_16x16x32_bf16(af[mi], bfr[ni], acc[mi][ni], 0, 0, 0);
        }

        asm volatile("s_waitcnt lgkmcnt(0)" ::: "memory");  // my ds_reads done -> safe to overwrite next iter
        __builtin_amdgcn_s_barrier();
        cur ^= 1;
    }

    // ---- epilogues ----
    if constexpr (MODE == 0) {
        ushort* Cp = (ushort*)Cptr_ + z * sC;
        #pragma unroll
        for (int mi = 0; mi < 4; ++mi) {
            const int row = m0 + wr * 64 + mi * 16 + g * 4;
            #pragma unroll
            for (int ni = 0; ni < 4; ++ni) {
                const int col = n0 + wc * 64 + ni * 16 + c;
                const float bv = HAS_BIAS ? bias[col] : 0.f;
                ushort v[4];
                #pragma unroll
                for (int r = 0; r < 4; ++r) v[r] = f2bf(acc[mi][ni][r] + bv);
                #pragma unroll
                for (int r = 0; r < 4; ++r) Cp[(long)(row + r) * ldc + col] = v[r];
                if constexpr (WRITE_T) {
                    const int bb = row >> rbshift;
                    const int ii = row & ((1 << rbshift) - 1);
                    *(ushort4*)&CTptr_[(long)bb * sCT + (long)col * ldct + ii] =
                        make_ushort4(v[0], v[1], v[2], v[3]);
                }
            }
        }
    } else if constexpr (MODE == 1) {
        ushort* Ep  = (ushort*)Cptr_ + z * sC;
        ushort* ETp = CTptr_ + z * sCT;
        float* rs = rsum_ + z * sSum;
        float* cs = csum_ + z * sSum;
        float rowpart[4][4] = {};
        float colpart[4] = {};
        #pragma unroll
        for (int mi = 0; mi < 4; ++mi) {
            const int row = m0 + wr * 64 + mi * 16 + g * 4;
            #pragma unroll
            for (int ni = 0; ni < 4; ++ni) {
                const int col = n0 + wc * 64 + ni * 16 + c;
                ushort v[4];
                #pragma unroll
                for (int r = 0; r < 4; ++r) {
                    const float s = acc[mi][ni][r];
                    const float t = 1.f - 2.f / (__expf(2.f * s) + 1.f);  // tanh(s)
                    const float e = __expf(t);
                    rowpart[mi][r] += e;
                    colpart[ni]    += e;
                    v[r] = f2bf(e);
                }
                #pragma unroll
                for (int r = 0; r < 4; ++r) Ep[(long)(row + r) * ldc + col] = v[r];
                *(ushort4*)&ETp[(long)col * ldct + row] = make_ushort4(v[0], v[1], v[2], v[3]);
            }
        }
        #pragma unroll
        for (int mi = 0; mi < 4; ++mi) {
            #pragma unroll
            for (int r = 0; r < 4; ++r) {
                float v = rowpart[mi][r];
                v += __shfl_xor(v, 1); v += __shfl_xor(v, 2);
                v += __shfl_xor(v, 4); v += __shfl_xor(v, 8);
                if (c == 0) atomicAdd(&rs[m0 + wr * 64 + mi * 16 + g * 4 + r], v);
            }
        }
        #pragma unroll
        for (int ni = 0; ni < 4; ++ni) {
            float v = colpart[ni];
            v += __shfl_xor(v, 16); v += __shfl_xor(v, 32);
            if (g == 0) atomicAdd(&cs[n0 + wc * 64 + ni * 16 + c], v);
        }
    } else if constexpr (MODE == 2) {
        const float* sc = scale_ + z * sSum;
        ushort* Cp = (ushort*)Cptr_ + z * sC;
        #pragma unroll
        for (int mi = 0; mi < 4; ++mi) {
            const int row = m0 + wr * 64 + mi * 16 + g * 4;
            float rcp[4];
            #pragma unroll
            for (int r = 0; r < 4; ++r) rcp[r] = 1.f / sc[row + r];
            #pragma unroll
            for (int ni = 0; ni < 4; ++ni) {
                const int col = n0 + wc * 64 + ni * 16 + c;
                #pragma unroll
                for (int r = 0; r < 4; ++r)
                    Cp[(long)(row + r) * ldc + col] = f2bf(acc[mi][ni][r] * rcp[r]);
            }
        }
    } else { // MODE == 3
        float* Co = (float*)Cptr_;
        #pragma unroll
        for (int mi = 0; mi < 4; ++mi) {
            const int row = m0 + wr * 64 + mi * 16 + g * 4;
            #pragma unroll
            for (int ni = 0; ni < 4; ++ni) {
                const int col = n0 + wc * 64 + ni * 16 + c;
                const float bv = bias[col];
                #pragma unroll
                for (int r = 0; r < 4; ++r) {
                    const long idx = (long)(row + r) * ldc + col;
                    Co[idx] = acc[mi][ni][r] + bv + resid_[idx];
                }
            }
        }
    }
}

// f32 -> bf16 elementwise (vectorized 8/thread, grid-stride)
__global__ __launch_bounds__(256)
void cast32to16(const float* __restrict__ in, ushort* __restrict__ out, long n) {
    const long stride = (long)gridDim.x * 256 * 8;
    for (long i = ((long)blockIdx.x * 256 + threadIdx.x) * 8; i < n; i += stride) {
        const float4 f0 = *(const float4*)(in + i);
        const float4 f1 = *(const float4*)(in + i + 4);
        uint4 w;
        w.x = (uint)f2bf(f0.x) | ((uint)f2bf(f0.y) << 16);
        w.y = (uint)f2bf(f0.z) | ((uint)f2bf(f0.w) << 16);
        w.z = (uint)f2bf(f1.x) | ((uint)f2bf(f1.y) << 16);
        w.w = (uint)f2bf(f1.z) | ((uint)f2bf(f1.w) << 16);
        *(uint4*)(out + i) = w;
    }
}

// f32 [R][C] -> bf16 [C][R]
__global__ __launch_bounds__(256)
void tcast(const float* __restrict__ in, ushort* __restrict__ out, int R, int C) {
    __shared__ float t[32][33];
    const int bx = blockIdx.x * 32, by = blockIdx.y * 32;
    const int tx = threadIdx.x, ty = threadIdx.y; // (32, 8)
    for (int i = ty; i < 32; i += 8) {
        const int r = by + i, cc = bx + tx;
        if (r < R && cc < C) t[i][tx] = in[(long)r * C + cc];
    }
    __syncthreads();
    for (int i = ty; i < 32; i += 8) {
        const int cc = bx + i, r = by + tx;
        if (cc < C && r < R) out[(long)cc * R + r] = f2bf(t[tx][i]);
    }
}

// in-place LayerNorm, one row per block
template<int D>
__global__ __launch_bounds__(256)
void ln_rows(float* __restrict__ y, const float* __restrict__ gam, const float* __restrict__ bet) {
    constexpr int NV = D / 256;
    const long row = blockIdx.x;
    float* p = y + row * D;
    const int tid = threadIdx.x;
    float v[NV];
    float s = 0.f, s2 = 0.f;
    #pragma unroll
    for (int k = 0; k < NV; ++k) {
        v[k] = p[tid + k * 256];
        s += v[k]; s2 += v[k] * v[k];
    }
    #pragma unroll
    for (int off = 1; off < 64; off <<= 1) {
        s  += __shfl_xor(s, off);
        s2 += __shfl_xor(s2, off);
    }
    __shared__ float ws[4], ws2[4];
    const int wave = tid >> 6, lane = tid & 63;
    if (lane == 0) { ws[wave] = s; ws2[wave] = s2; }
    __syncthreads();
    s  = ws[0] + ws[1] + ws[2] + ws[3];
    s2 = ws2[0] + ws2[1] + ws2[2] + ws2[3];
    const float mu  = s / D;
    const float var = s2 / D - mu * mu;
    const float rstd = rsqrtf(var + 1e-5f);
    #pragma unroll
    for (int k = 0; k < NV; ++k) {
        const int i = tid + k * 256;
        p[i] = (v[k] - mu) * rstd * gam[i] + bet[i];
    }
}

extern "C" void kernel_launch(void* const* d_in, const int* in_sizes, int n_in,
                              void* d_out, int out_size, void* d_ws, size_t ws_size,
                              hipStream_t stream)
{
    (void)in_sizes; (void)n_in; (void)out_size; (void)ws_size;
    const float* z_a    = (const float*)d_in[0];
    const float* z_b    = (const float*)d_in[1];
    const float* Wa     = (const float*)d_in[2];
    const float* ba     = (const float*)d_in[3];
    const float* Wb     = (const float*)d_in[4];
    const float* bb     = (const float*)d_in[5];
    const float* Wco    = (const float*)d_in[6];
    const float* Woa    = (const float*)d_in[7];
    const float* boa    = (const float*)d_in[8];
    const float* Wob    = (const float*)d_in[9];
    const float* bob    = (const float*)d_in[10];
    const float* ga     = (const float*)d_in[11];
    const float* beta_a = (const float*)d_in[12];
    const float* gb     = (const float*)d_in[13];
    const float* beta_b = (const float*)d_in[14];

    const int Bn = 16, LA = 2048, LB = 2048, DA = 768, DB = 512, DH = 512;
    const long MA = (long)Bn * LA;
    const long MB = (long)Bn * LB;

    char* w = (char*)d_ws;
    size_t off = 0;
    auto alc = [&](size_t bytes) { void* p = w + off; off += (bytes + 255) & ~(size_t)255; return p; };

    ushort* WaT  = (ushort*)alc((size_t)DH * DA * 2);
    ushort* WbT  = (ushort*)alc((size_t)DH * DB * 2);
    ushort* WcoT = (ushort*)alc((size_t)DH * DH * 2);
    ushort* WoaT = (ushort*)alc((size_t)DA * DH * 2);
    ushort* WobT = (ushort*)alc((size_t)DB * DH * 2);
    ushort* h_a  = (ushort*)alc((size_t)MA * DH * 2);
    ushort* h_b  = (ushort*)alc((size_t)MB * DH * 2);
    ushort* h_aT = (ushort*)alc((size_t)Bn * DH * LA * 2);
    ushort* h_bT = (ushort*)alc((size_t)Bn * DH * LB * 2);
    ushort* Ma   = (ushort*)alc((size_t)MA * DH * 2);
    ushort* E    = (ushort*)alc((size_t)Bn * LA * LB * 2);
    ushort* ET   = (ushort*)alc((size_t)Bn * LB * LA * 2);
    ushort* Pa   = (ushort*)alc((size_t)MA * DH * 2);
    ushort* Pb   = (ushort*)alc((size_t)MB * DH * 2);
    float*  rsum = (float*)alc((size_t)Bn * LA * 4);
    float*  csum = (float*)alc((size_t)Bn * LB * 4);

    // bf16 copies of z_a, z_b aliased into E's region (dead before E is written)
    ushort* za16 = E;                       // MA*DA = 25.2M ushorts
    ushort* zb16 = E + (size_t)MA * DA;     // MB*DB = 16.8M ushorts (total 84MB < 268MB)

    dim3 blk(256, 1, 1);
    dim3 tb(32, 8, 1);

    // weight transposes (f32 -> bf16, [K][N] -> [N][K])
    tcast<<<dim3(DH / 32, DA / 32, 1), tb, 0, stream>>>(Wa,  WaT,  DA, DH);
    tcast<<<dim3(DH / 32, DB / 32, 1), tb, 0, stream>>>(Wb,  WbT,  DB, DH);
    tcast<<<dim3(DH / 32, DH / 32, 1), tb, 0, stream>>>(Wco, WcoT, DH, DH);
    tcast<<<dim3(DA / 32, DH / 32, 1), tb, 0, stream>>>(Woa, WoaT, DH, DA);
    tcast<<<dim3(DB / 32, DH / 32, 1), tb, 0, stream>>>(Wob, WobT, DH, DB);

    // activations f32 -> bf16
    cast32to16<<<dim3(2048, 1, 1), blk, 0, stream>>>(z_a, za16, MA * DA);
    cast32to16<<<dim3(2048, 1, 1), blk, 0, stream>>>(z_b, zb16, MB * DB);

    // zero softmax denominators (rsum & csum are contiguous)
    hipMemsetAsync(rsum, 0, (size_t)Bn * (LA + LB) * sizeof(float), stream);

    // h_a = z_a @ Wa + ba   (also writes h_aT per batch)
    gemm_bt<0, true, true><<<dim3(MA / BM, DH / BN, 1), blk, 0, stream>>>(
        za16, WaT, h_a, h_aT, ba, nullptr, nullptr, nullptr, nullptr,
        (int)MA, DH, DA, DA, DA, DH, 0, 0, 0, (long)DH * LA, 0, LA, 11);

    // h_b = z_b @ Wb + bb   (also writes h_bT per batch)
    gemm_bt<0, true, true><<<dim3(MB / BM, DH / BN, 1), blk, 0, stream>>>(
        zb16, WbT, h_b, h_bT, bb, nullptr, nullptr, nullptr, nullptr,
        (int)MB, DH, DB, DB, DB, DH, 0, 0, 0, (long)DH * LB, 0, LB, 11);

    // Ma = h_a @ W_co
    gemm_bt<0, false, false><<<dim3(MA / BM, DH / BN, 1), blk, 0, stream>>>(
        h_a, WcoT, Ma, nullptr, nullptr, nullptr, nullptr, nullptr, nullptr,
        (int)MA, DH, DH, DH, DH, DH, 0, 0, 0, 0, 0, 0, 0);

    // scores: E = exp(tanh(Ma @ h_b^T)), E^T, rowsum, colsum  (batched)
    gemm_bt<1, false, false><<<dim3(LA / BM, LB / BN, Bn), blk, 0, stream>>>(
        Ma, h_b, E, ET, nullptr, nullptr, rsum, csum, nullptr,
        LA, LB, DH, DH, DH, LB,
        (long)LA * DH, (long)LB * DH, (long)LA * LB, (long)LB * LA, LA, LA, 0);

    // Pa = (E @ h_b) / rowsum  (batched)
    gemm_bt<2, false, false><<<dim3(LA / BM, DH / BN, Bn), blk, 0, stream>>>(
        E, h_bT, Pa, nullptr, nullptr, nullptr, nullptr, nullptr, rsum,
        LA, DH, LB, LB, LB, DH,
        (long)LA * LB, (long)DH * LB, (long)LA * DH, 0, LA, 0, 0);

    // Pb = (E^T @ h_a) / colsum  (batched)
    gemm_bt<2, false, false><<<dim3(LB / BM, DH / BN, Bn), blk, 0, stream>>>(
        ET, h_aT, Pb, nullptr, nullptr, nullptr, nullptr, nullptr, csum,
        LB, DH, LA, LA, LA, DH,
        (long)LB * LA, (long)DH * LA, (long)LB * DH, 0, LB, 0, 0);

    float* outA = (float*)d_out;
    float* outB = outA + MA * DA;

    // z_a_pre = Pa @ Woa + boa + z_a  -> d_out (f32, in place for LN)
    gemm_bt<3, true, false><<<dim3(MA / BM, DA / BN, 1), blk, 0, stream>>>(
        Pa, WoaT, outA, nullptr, boa, z_a, nullptr, nullptr, nullptr,
        (int)MA, DA, DH, DH, DH, DA, 0, 0, 0, 0, 0, 0, 0);

    // z_b_pre = Pb @ Wob + bob + z_b  -> d_out
    gemm_bt<3, true, false><<<dim3(MB / BM, DB / BN, 1), blk, 0, stream>>>(
        Pb, WobT, outB, nullptr, bob, z_b, nullptr, nullptr, nullptr,
        (int)MB, DB, DH, DH, DH, DB, 0, 0, 0, 0, 0, 0, 0);

    // LayerNorms in place on d_out
    ln_rows<768><<<dim3((unsigned)MA, 1, 1), blk, 0, stream>>>(outA, ga, beta_a);
    ln_rows<512><<<dim3((unsigned)MB, 1, 1), blk, 0, stream>>>(outB, gb, beta_b);
}

// Round 4
// 781.588 us; speedup vs baseline: 1.0388x; 1.0388x over previous
//
#include <hip/hip_runtime.h>
#include <stdint.h>

typedef short bf16x8 __attribute__((ext_vector_type(8)));
typedef float f32x4 __attribute__((ext_vector_type(4)));

#define BM 256
#define BN 128
#define BK 64
// per-buf LDS: A 256*64 + B 128*64 ushorts = 24576 ushorts = 48KB; 3 bufs = 144KB
#define ABUF_U 16384
#define BUF_U  24576

#define AS1 __attribute__((address_space(1)))
#define AS3 __attribute__((address_space(3)))

__device__ __forceinline__ ushort f2bf(float x) {
    uint32_t u = __float_as_uint(x);
    u += 0x7FFFu + ((u >> 16) & 1u);
    return (ushort)(u >> 16);
}

__device__ __forceinline__ void gload16(const void* g, void* l) {
    __builtin_amdgcn_global_load_lds((const AS1 void*)g, (AS3 void*)l, 16, 0, 0);
}

// C[M,N] = A[M,K] * B[N,K]^T, bf16 MFMA 16x16x32.
// 256x128 tile, 512 threads (8 waves: 2M x 4N, per-wave 128x32, acc[8][2]).
// 3 LDS tile-buffers, window t computes tile t (buf t%3) while staging tile
// t+2 into buf (t+2)%3 (free: its old tile t-1 was consumed in window t-1).
// 2 phases/window; per phase: 10 ds_read_b128 + 3 global_load_lds ->
// barrier -> setprio(1) 16 MFMA setprio(0) -> barrier.
// vmcnt(6) once per window (= the 6 loads of the newest tile in flight).
// MODE 0: bf16 out = acc (+bias), optional transposed copy (per-batch [col][row])
// MODE 1: scores: e=exp(tanh(acc)); write E + E^T bf16; atomic rowsum/colsum
// MODE 2: bf16 out = acc / scale[row]
// MODE 3: f32 out = acc + bias[col] + resid[row,col]
template<int MODE, bool HAS_BIAS, bool WRITE_T>
__global__ __launch_bounds__(512)
void gemm_bt(const ushort* __restrict__ Aptr_, const ushort* __restrict__ Bptr_,
             void* __restrict__ Cptr_, ushort* __restrict__ CTptr_,
             const float* __restrict__ bias, const float* __restrict__ resid_,
             float* __restrict__ rsum_, float* __restrict__ csum_,
             const float* __restrict__ scale_,
             int M, int N, int K, int lda, int ldb, int ldc,
             long sA, long sB, long sC, long sCT, long sSum,
             int ldct, int rbshift)
{
    extern __shared__ ushort smem[];   // 3 * BUF_U ushorts

    const int z    = blockIdx.z;
    const int m0   = blockIdx.x * BM;
    const int n0   = blockIdx.y * BN;
    const int tid  = threadIdx.x;
    const int lane = tid & 63;
    const int wave = tid >> 6;
    const int wr   = wave >> 2;        // 0..1 -> rows wr*128..+128
    const int wcn  = wave & 3;         // 0..3 -> cols wcn*32..+32
    const int g    = lane >> 4, c = lane & 15;

    const ushort* Ap = Aptr_ + z * sA;
    const ushort* Bp = Bptr_ + z * sB;

    // per-thread staging offsets (XOR-swizzled global source, linear LDS dest)
    long aoff[4]; int aLds[4];
    #pragma unroll
    for (int u = 0; u < 4; ++u) {
        const int li  = u * 512 + tid;       // A chunk 0..2047
        const int row = li >> 3;             // 0..255
        const int gck = (li & 7) ^ (row & 7);
        aoff[u] = (long)(m0 + row) * lda + gck * 8;
        aLds[u] = li * 8;
    }
    long boff[2]; int bLds[2];
    #pragma unroll
    for (int v = 0; v < 2; ++v) {
        const int li  = v * 512 + tid;       // B chunk 0..1023
        const int row = li >> 3;             // 0..127
        const int gck = (li & 7) ^ (row & 7);
        boff[v] = (long)(n0 + row) * ldb + gck * 8;
        bLds[v] = li * 8;
    }

    auto stage3 = [&](int kt, ushort* As, ushort* Bs, int q) {
        if (q == 0) {
            gload16(Ap + aoff[0] + kt, As + aLds[0]);
            gload16(Ap + aoff[1] + kt, As + aLds[1]);
            gload16(Ap + aoff[2] + kt, As + aLds[2]);
        } else {
            gload16(Ap + aoff[3] + kt, As + aLds[3]);
            gload16(Bp + boff[0] + kt, Bs + bLds[0]);
            gload16(Bp + boff[1] + kt, Bs + bLds[1]);
        }
    };

    f32x4 acc[8][2] = {};

    const int nk = K / BK;
    // prologue: stage tiles 0 (buf0) and 1 (buf1) = 12 loads/thread
    stage3(0, smem, smem + ABUF_U, 0);
    stage3(0, smem, smem + ABUF_U, 1);
    stage3(BK, smem + BUF_U, smem + BUF_U + ABUF_U, 0);
    stage3(BK, smem + BUF_U, smem + BUF_U + ABUF_U, 1);
    asm volatile("s_waitcnt vmcnt(6)" ::: "memory");   // tile 0 landed; tile 1 in flight
    __builtin_amdgcn_s_barrier();

    int bt = 0;
    for (int t = 0; t < nk; ++t) {
        const int b2 = (bt + 2 >= 3) ? bt - 1 : bt + 2;   // buf for tile t+2
        ushort* As  = smem + bt * BUF_U;
        ushort* Bs  = As + ABUF_U;
        ushort* As2 = smem + b2 * BUF_U;
        ushort* Bs2 = As2 + ABUF_U;
        const bool pf = (t + 2 < nk);

        #pragma unroll
        for (int q = 0; q < 2; ++q) {
            bf16x8 af[8], bfr[2];
            #pragma unroll
            for (int mi = 0; mi < 8; ++mi) {
                const int row = wr * 128 + mi * 16 + c;
                const int ckq = (q * 4 + g) ^ (row & 7);
                af[mi] = *(const bf16x8*)&As[row * BK + ckq * 8];
            }
            #pragma unroll
            for (int ni = 0; ni < 2; ++ni) {
                const int row = wcn * 32 + ni * 16 + c;
                const int ckq = (q * 4 + g) ^ (row & 7);
                bfr[ni] = *(const bf16x8*)&Bs[row * BK + ckq * 8];
            }
            if (pf) stage3((t + 2) * BK, As2, Bs2, q);
            if (q == 1) {
                if (pf) asm volatile("s_waitcnt vmcnt(6)" ::: "memory");  // tile t+1 landed
                else    asm volatile("s_waitcnt vmcnt(0)" ::: "memory");  // tail drain
            }
            asm volatile("" ::: "memory");
            __builtin_amdgcn_s_barrier();
            __builtin_amdgcn_s_setprio(1);
            #pragma unroll
            for (int mi = 0; mi < 8; ++mi)
                #pragma unroll
                for (int ni = 0; ni < 2; ++ni)
                    acc[mi][ni] = __builtin_amdgcn_mfma_f32_16x16x32_bf16(af[mi], bfr[ni], acc[mi][ni], 0, 0, 0);
            __builtin_amdgcn_s_setprio(0);
            asm volatile("" ::: "memory");
            __builtin_amdgcn_s_barrier();
        }
        bt = (bt + 1 == 3) ? 0 : bt + 1;
    }

    // ---- epilogues ----
    if constexpr (MODE == 0) {
        ushort* Cp = (ushort*)Cptr_ + z * sC;
        #pragma unroll
        for (int mi = 0; mi < 8; ++mi) {
            const int row = m0 + wr * 128 + mi * 16 + g * 4;
            #pragma unroll
            for (int ni = 0; ni < 2; ++ni) {
                const int col = n0 + wcn * 32 + ni * 16 + c;
                const float bv = HAS_BIAS ? bias[col] : 0.f;
                ushort v[4];
                #pragma unroll
                for (int r = 0; r < 4; ++r) v[r] = f2bf(acc[mi][ni][r] + bv);
                #pragma unroll
                for (int r = 0; r < 4; ++r) Cp[(long)(row + r) * ldc + col] = v[r];
                if constexpr (WRITE_T) {
                    const int bb = row >> rbshift;
                    const int ii = row & ((1 << rbshift) - 1);
                    *(ushort4*)&CTptr_[(long)bb * sCT + (long)col * ldct + ii] =
                        make_ushort4(v[0], v[1], v[2], v[3]);
                }
            }
        }
    } else if constexpr (MODE == 1) {
        ushort* Ep  = (ushort*)Cptr_ + z * sC;
        ushort* ETp = CTptr_ + z * sCT;
        float* rs = rsum_ + z * sSum;
        float* cs = csum_ + z * sSum;
        float rowpart[8][4] = {};
        float colpart[2] = {};
        #pragma unroll
        for (int mi = 0; mi < 8; ++mi) {
            const int row = m0 + wr * 128 + mi * 16 + g * 4;
            #pragma unroll
            for (int ni = 0; ni < 2; ++ni) {
                const int col = n0 + wcn * 32 + ni * 16 + c;
                ushort v[4];
                #pragma unroll
                for (int r = 0; r < 4; ++r) {
                    const float s = acc[mi][ni][r];
                    const float t = 1.f - 2.f / (__expf(2.f * s) + 1.f);  // tanh(s)
                    const float e = __expf(t);
                    rowpart[mi][r] += e;
                    colpart[ni]    += e;
                    v[r] = f2bf(e);
                }
                #pragma unroll
                for (int r = 0; r < 4; ++r) Ep[(long)(row + r) * ldc + col] = v[r];
                *(ushort4*)&ETp[(long)col * ldct + row] = make_ushort4(v[0], v[1], v[2], v[3]);
            }
        }
        #pragma unroll
        for (int mi = 0; mi < 8; ++mi) {
            #pragma unroll
            for (int r = 0; r < 4; ++r) {
                float v = rowpart[mi][r];
                v += __shfl_xor(v, 1); v += __shfl_xor(v, 2);
                v += __shfl_xor(v, 4); v += __shfl_xor(v, 8);
                if (c == 0) atomicAdd(&rs[m0 + wr * 128 + mi * 16 + g * 4 + r], v);
            }
        }
        #pragma unroll
        for (int ni = 0; ni < 2; ++ni) {
            float v = colpart[ni];
            v += __shfl_xor(v, 16); v += __shfl_xor(v, 32);
            if (g == 0) atomicAdd(&cs[n0 + wcn * 32 + ni * 16 + c], v);
        }
    } else if constexpr (MODE == 2) {
        const float* sc = scale_ + z * sSum;
        ushort* Cp = (ushort*)Cptr_ + z * sC;
        #pragma unroll
        for (int mi = 0; mi < 8; ++mi) {
            const int row = m0 + wr * 128 + mi * 16 + g * 4;
            float rcp[4];
            #pragma unroll
            for (int r = 0; r < 4; ++r) rcp[r] = 1.f / sc[row + r];
            #pragma unroll
            for (int ni = 0; ni < 2; ++ni) {
                const int col = n0 + wcn * 32 + ni * 16 + c;
                #pragma unroll
                for (int r = 0; r < 4; ++r)
                    Cp[(long)(row + r) * ldc + col] = f2bf(acc[mi][ni][r] * rcp[r]);
            }
        }
    } else { // MODE == 3
        float* Co = (float*)Cptr_;
        #pragma unroll
        for (int mi = 0; mi < 8; ++mi) {
            const int row = m0 + wr * 128 + mi * 16 + g * 4;
            #pragma unroll
            for (int ni = 0; ni < 2; ++ni) {
                const int col = n0 + wcn * 32 + ni * 16 + c;
                const float bv = bias[col];
                #pragma unroll
                for (int r = 0; r < 4; ++r) {
                    const long idx = (long)(row + r) * ldc + col;
                    Co[idx] = acc[mi][ni][r] + bv + resid_[idx];
                }
            }
        }
    }
}

// f32 -> bf16 elementwise (vectorized 8/thread, grid-stride)
__global__ __launch_bounds__(256)
void cast32to16(const float* __restrict__ in, ushort* __restrict__ out, long n) {
    const long stride = (long)gridDim.x * 256 * 8;
    for (long i = ((long)blockIdx.x * 256 + threadIdx.x) * 8; i < n; i += stride) {
        const float4 f0 = *(const float4*)(in + i);
        const float4 f1 = *(const float4*)(in + i + 4);
        uint4 w;
        w.x = (uint)f2bf(f0.x) | ((uint)f2bf(f0.y) << 16);
        w.y = (uint)f2bf(f0.z) | ((uint)f2bf(f0.w) << 16);
        w.z = (uint)f2bf(f1.x) | ((uint)f2bf(f1.y) << 16);
        w.w = (uint)f2bf(f1.z) | ((uint)f2bf(f1.w) << 16);
        *(uint4*)(out + i) = w;
    }
}

// f32 [R][C] -> bf16 [C][R]
__global__ __launch_bounds__(256)
void tcast(const float* __restrict__ in, ushort* __restrict__ out, int R, int C) {
    __shared__ float t[32][33];
    const int bx = blockIdx.x * 32, by = blockIdx.y * 32;
    const int tx = threadIdx.x, ty = threadIdx.y; // (32, 8)
    for (int i = ty; i < 32; i += 8) {
        const int r = by + i, cc = bx + tx;
        if (r < R && cc < C) t[i][tx] = in[(long)r * C + cc];
    }
    __syncthreads();
    for (int i = ty; i < 32; i += 8) {
        const int cc = bx + i, r = by + tx;
        if (cc < C && r < R) out[(long)cc * R + r] = f2bf(t[tx][i]);
    }
}

// in-place LayerNorm, one row per block
template<int D>
__global__ __launch_bounds__(256)
void ln_rows(float* __restrict__ y, const float* __restrict__ gam, const float* __restrict__ bet) {
    constexpr int NV = D / 256;
    const long row = blockIdx.x;
    float* p = y + row * D;
    const int tid = threadIdx.x;
    float v[NV];
    float s = 0.f, s2 = 0.f;
    #pragma unroll
    for (int k = 0; k < NV; ++k) {
        v[k] = p[tid + k * 256];
        s += v[k]; s2 += v[k] * v[k];
    }
    #pragma unroll
    for (int off = 1; off < 64; off <<= 1) {
        s  += __shfl_xor(s, off);
        s2 += __shfl_xor(s2, off);
    }
    __shared__ float ws[4], ws2[4];
    const int wave = tid >> 6, lane = tid & 63;
    if (lane == 0) { ws[wave] = s; ws2[wave] = s2; }
    __syncthreads();
    s  = ws[0] + ws[1] + ws[2] + ws[3];
    s2 = ws2[0] + ws2[1] + ws2[2] + ws2[3];
    const float mu  = s / D;
    const float var = s2 / D - mu * mu;
    const float rstd = rsqrtf(var + 1e-5f);
    #pragma unroll
    for (int k = 0; k < NV; ++k) {
        const int i = tid + k * 256;
        p[i] = (v[k] - mu) * rstd * gam[i] + bet[i];
    }
}

extern "C" void kernel_launch(void* const* d_in, const int* in_sizes, int n_in,
                              void* d_out, int out_size, void* d_ws, size_t ws_size,
                              hipStream_t stream)
{
    (void)in_sizes; (void)n_in; (void)out_size; (void)ws_size;
    const float* z_a    = (const float*)d_in[0];
    const float* z_b    = (const float*)d_in[1];
    const float* Wa     = (const float*)d_in[2];
    const float* ba     = (const float*)d_in[3];
    const float* Wb     = (const float*)d_in[4];
    const float* bb     = (const float*)d_in[5];
    const float* Wco    = (const float*)d_in[6];
    const float* Woa    = (const float*)d_in[7];
    const float* boa    = (const float*)d_in[8];
    const float* Wob    = (const float*)d_in[9];
    const float* bob    = (const float*)d_in[10];
    const float* ga     = (const float*)d_in[11];
    const float* beta_a = (const float*)d_in[12];
    const float* gb     = (const float*)d_in[13];
    const float* beta_b = (const float*)d_in[14];

    const int Bn = 16, LA = 2048, LB = 2048, DA = 768, DB = 512, DH = 512;
    const long MA = (long)Bn * LA;
    const long MB = (long)Bn * LB;

    char* w = (char*)d_ws;
    size_t off = 0;
    auto alc = [&](size_t bytes) { void* p = w + off; off += (bytes + 255) & ~(size_t)255; return p; };

    ushort* WaT  = (ushort*)alc((size_t)DH * DA * 2);
    ushort* WbT  = (ushort*)alc((size_t)DH * DB * 2);
    ushort* WcoT = (ushort*)alc((size_t)DH * DH * 2);
    ushort* WoaT = (ushort*)alc((size_t)DA * DH * 2);
    ushort* WobT = (ushort*)alc((size_t)DB * DH * 2);
    ushort* h_a  = (ushort*)alc((size_t)MA * DH * 2);
    ushort* h_b  = (ushort*)alc((size_t)MB * DH * 2);
    ushort* h_aT = (ushort*)alc((size_t)Bn * DH * LA * 2);
    ushort* h_bT = (ushort*)alc((size_t)Bn * DH * LB * 2);
    ushort* Ma   = (ushort*)alc((size_t)MA * DH * 2);
    ushort* E    = (ushort*)alc((size_t)Bn * LA * LB * 2);
    ushort* ET   = (ushort*)alc((size_t)Bn * LB * LA * 2);
    ushort* Pa   = (ushort*)alc((size_t)MA * DH * 2);
    ushort* Pb   = (ushort*)alc((size_t)MB * DH * 2);
    float*  rsum = (float*)alc((size_t)Bn * LA * 4);
    float*  csum = (float*)alc((size_t)Bn * LB * 4);

    // bf16 copies of z_a, z_b aliased into E's region (dead before E is written)
    ushort* za16 = E;
    ushort* zb16 = E + (size_t)MA * DA;

    dim3 blk(512, 1, 1);
    dim3 blk256(256, 1, 1);
    dim3 tb(32, 8, 1);
    const int SHM = 3 * BUF_U * 2;   // 147456 B dynamic LDS

    // weight transposes (f32 -> bf16, [K][N] -> [N][K])
    tcast<<<dim3(DH / 32, DA / 32, 1), tb, 0, stream>>>(Wa,  WaT,  DA, DH);
    tcast<<<dim3(DH / 32, DB / 32, 1), tb, 0, stream>>>(Wb,  WbT,  DB, DH);
    tcast<<<dim3(DH / 32, DH / 32, 1), tb, 0, stream>>>(Wco, WcoT, DH, DH);
    tcast<<<dim3(DA / 32, DH / 32, 1), tb, 0, stream>>>(Woa, WoaT, DH, DA);
    tcast<<<dim3(DB / 32, DH / 32, 1), tb, 0, stream>>>(Wob, WobT, DH, DB);

    // activations f32 -> bf16
    cast32to16<<<dim3(2048, 1, 1), blk256, 0, stream>>>(z_a, za16, MA * DA);
    cast32to16<<<dim3(2048, 1, 1), blk256, 0, stream>>>(z_b, zb16, MB * DB);

    // zero softmax denominators (rsum & csum are contiguous)
    hipMemsetAsync(rsum, 0, (size_t)Bn * (LA + LB) * sizeof(float), stream);

    // h_a = z_a @ Wa + ba   (also writes h_aT per batch)
    gemm_bt<0, true, true><<<dim3(MA / BM, DH / BN, 1), blk, SHM, stream>>>(
        za16, WaT, h_a, h_aT, ba, nullptr, nullptr, nullptr, nullptr,
        (int)MA, DH, DA, DA, DA, DH, 0, 0, 0, (long)DH * LA, 0, LA, 11);

    // h_b = z_b @ Wb + bb   (also writes h_bT per batch)
    gemm_bt<0, true, true><<<dim3(MB / BM, DH / BN, 1), blk, SHM, stream>>>(
        zb16, WbT, h_b, h_bT, bb, nullptr, nullptr, nullptr, nullptr,
        (int)MB, DH, DB, DB, DB, DH, 0, 0, 0, (long)DH * LB, 0, LB, 11);

    // Ma = h_a @ W_co
    gemm_bt<0, false, false><<<dim3(MA / BM, DH / BN, 1), blk, SHM, stream>>>(
        h_a, WcoT, Ma, nullptr, nullptr, nullptr, nullptr, nullptr, nullptr,
        (int)MA, DH, DH, DH, DH, DH, 0, 0, 0, 0, 0, 0, 0);

    // scores: E = exp(tanh(Ma @ h_b^T)), E^T, rowsum, colsum  (batched)
    gemm_bt<1, false, false><<<dim3(LA / BM, LB / BN, Bn), blk, SHM, stream>>>(
        Ma, h_b, E, ET, nullptr, nullptr, rsum, csum, nullptr,
        LA, LB, DH, DH, DH, LB,
        (long)LA * DH, (long)LB * DH, (long)LA * LB, (long)LB * LA, LA, LA, 0);

    // Pa = (E @ h_b) / rowsum  (batched)
    gemm_bt<2, false, false><<<dim3(LA / BM, DH / BN, Bn), blk, SHM, stream>>>(
        E, h_bT, Pa, nullptr, nullptr, nullptr, nullptr, nullptr, rsum,
        LA, DH, LB, LB, LB, DH,
        (long)LA * LB, (long)DH * LB, (long)LA * DH, 0, LA, 0, 0);

    // Pb = (E^T @ h_a) / colsum  (batched)
    gemm_bt<2, false, false><<<dim3(LB / BM, DH / BN, Bn), blk, SHM, stream>>>(
        ET, h_aT, Pb, nullptr, nullptr, nullptr, nullptr, nullptr, csum,
        LB, DH, LA, LA, LA, DH,
        (long)LB * LA, (long)DH * LA, (long)LB * DH, 0, LB, 0, 0);

    float* outA = (float*)d_out;
    float* outB = outA + MA * DA;

    // z_a_pre = Pa @ Woa + boa + z_a  -> d_out (f32, in place for LN)
    gemm_bt<3, true, false><<<dim3(MA / BM, DA / BN, 1), blk, SHM, stream>>>(
        Pa, WoaT, outA, nullptr, boa, z_a, nullptr, nullptr, nullptr,
        (int)MA, DA, DH, DH, DH, DA, 0, 0, 0, 0, 0, 0, 0);

    // z_b_pre = Pb @ Wob + bob + z_b  -> d_out
    gemm_bt<3, true, false><<<dim3(MB / BM, DB / BN, 1), blk, SHM, stream>>>(
        Pb, WobT, outB, nullptr, bob, z_b, nullptr, nullptr, nullptr,
        (int)MB, DB, DH, DH, DH, DB, 0, 0, 0, 0, 0, 0, 0);

    // LayerNorms in place on d_out
    ln_rows<768><<<dim3((unsigned)MA, 1, 1), blk256, 0, stream>>>(outA, ga, beta_a);
    ln_rows<512><<<dim3((unsigned)MB, 1, 1), blk256, 0, stream>>>(outB, gb, beta_b);
}

// Round 5
// 719.865 us; speedup vs baseline: 1.1279x; 1.0857x over previous
//
#include <hip/hip_runtime.h>
#include <stdint.h>

typedef short bf16x8 __attribute__((ext_vector_type(8)));
typedef float f32x4 __attribute__((ext_vector_type(4)));

#define BM 256
#define BN 256
#define BK 64
#define ABUF_U 16384   // 256*64 ushorts (32KB) A region
#define BUF_U  32768   // A+B per buffer in ushorts (64KB); 2 buffers = 128KB

#define AS1 __attribute__((address_space(1)))
#define AS3 __attribute__((address_space(3)))

__device__ __forceinline__ ushort f2bf(float x) {
    uint32_t u = __float_as_uint(x);
    u += 0x7FFFu + ((u >> 16) & 1u);
    return (ushort)(u >> 16);
}

__device__ __forceinline__ void gload16(const void* g, void* l) {
    __builtin_amdgcn_global_load_lds((const AS1 void*)g, (AS3 void*)l, 16, 0, 0);
}

// issue 2 staging loads (chunks i0, i0+1 of 8) for K-offset kt into buffer buf
#define ISSUE2(kt, buf, i0)                                                          \
    do {                                                                             \
        gload16(((i0) < 4 ? Ap : Bp) + goff[i0] + (kt), smem + (buf)*BUF_U + loff[i0]); \
        gload16((((i0)+1) < 4 ? Ap : Bp) + goff[(i0)+1] + (kt), smem + (buf)*BUF_U + loff[(i0)+1]); \
    } while (0)

// C[M,N] = A[M,K] * B[N,K]^T, bf16 MFMA 16x16x32.
// 256x256 tile, 512 threads (8 waves: 2M x 4N, per-wave 128x64, acc[8][4]).
// 8-phase-style schedule (T3+T4+T5): double-buffered LDS (2x64KB), per tile:
//   entry: issue 2 prefetch gloads -> vmcnt(2) -> barrier
//   4 phases, each: {ds_read frag subtile || issue 2 prefetch gloads ->
//     s_barrier -> lgkmcnt(0)+sched_barrier -> setprio(1) 16 MFMA setprio(0) -> s_barrier}
// A-frags (8) loaded in phases 0,2 and reused in 1,3. Never vmcnt(0) mid-loop.
// MODE 0: bf16 out = acc (+bias), optional transposed copy (per-batch [col][row])
// MODE 1: scores: e=exp(tanh(acc)); write E + E^T bf16; atomic rowsum/colsum
// MODE 2: bf16 out = acc / scale[row]
// MODE 3: f32 out = acc + bias[col] + resid[row,col]
template<int MODE, bool HAS_BIAS, bool WRITE_T>
__global__ __launch_bounds__(512, 2)
void gemm_bt(const ushort* __restrict__ Aptr_, const ushort* __restrict__ Bptr_,
             void* __restrict__ Cptr_, ushort* __restrict__ CTptr_,
             const float* __restrict__ bias, const float* __restrict__ resid_,
             float* __restrict__ rsum_, float* __restrict__ csum_,
             const float* __restrict__ scale_,
             int M, int N, int K, int lda, int ldb, int ldc,
             long sA, long sB, long sC, long sCT, long sSum,
             int ldct, int rbshift)
{
    extern __shared__ ushort smem[];   // 2 * BUF_U ushorts

    const int z    = blockIdx.z;
    const int m0   = blockIdx.x * BM;
    const int n0   = blockIdx.y * BN;
    const int tid  = threadIdx.x;
    const int lane = tid & 63;
    const int wave = tid >> 6;
    const int wr   = wave >> 2;        // 0..1 -> rows wr*128..+128
    const int wcn  = wave & 3;         // 0..3 -> cols wcn*64..+64
    const int g    = lane >> 4, c = lane & 15;

    const ushort* Ap = Aptr_ + z * sA;
    const ushort* Bp = Bptr_ + z * sB;

    // staging: linear LDS dest (wave-uniform base + lane*16), XOR-swizzled
    // global source chunk; ds_read applies the same XOR -> conflict-free.
    long goff[8]; int loff[8];
    #pragma unroll
    for (int u = 0; u < 4; ++u) {
        const int li  = u * 512 + tid;       // chunk 0..2047 (A and B each)
        const int row = li >> 3;             // 0..255
        const int gck = (li & 7) ^ (row & 7);
        goff[u]     = (long)(m0 + row) * lda + gck * 8;
        loff[u]     = li * 8;
        goff[u + 4] = (long)(n0 + row) * ldb + gck * 8;
        loff[u + 4] = ABUF_U + li * 8;
    }

    f32x4 acc[8][4] = {};

    const int nk = K / BK;
    // prologue: stage tile 0 into buf 0 (8 loads/thread)
    ISSUE2(0, 0, 0); ISSUE2(0, 0, 2); ISSUE2(0, 0, 4); ISSUE2(0, 0, 6);

    for (int t = 0; t < nk; ++t) {
        const int cur = t & 1, nxt = cur ^ 1;
        const ushort* As = smem + cur * BUF_U;
        const ushort* Bs = As + ABUF_U;
        const bool pf = (t + 1 < nk);
        const int kt1 = (t + 1) * BK;

        if (pf) {
            ISSUE2(kt1, nxt, 0);
            asm volatile("s_waitcnt vmcnt(2)" ::: "memory");  // tile t landed; 2 prefetch in flight
        } else {
            asm volatile("s_waitcnt vmcnt(0)" ::: "memory");  // tail drain
        }
        __builtin_amdgcn_s_barrier();

        bf16x8 af[8], bfr2[2];

        auto ldA = [&](int kk) {
            #pragma unroll
            for (int mi = 0; mi < 8; ++mi) {
                const int row = wr * 128 + mi * 16 + c;
                const int ckq = (kk * 4 + g) ^ (row & 7);
                af[mi] = *(const bf16x8*)&As[row * BK + ckq * 8];
            }
        };
        auto ldB = [&](int kk, int nh) {
            #pragma unroll
            for (int u = 0; u < 2; ++u) {
                const int row = wcn * 64 + (nh * 2 + u) * 16 + c;
                const int ckq = (kk * 4 + g) ^ (row & 7);
                bfr2[u] = *(const bf16x8*)&Bs[row * BK + ckq * 8];
            }
        };
        auto mm = [&](int nh) {
            __builtin_amdgcn_s_setprio(1);
            #pragma unroll
            for (int mi = 0; mi < 8; ++mi)
                #pragma unroll
                for (int u = 0; u < 2; ++u)
                    acc[mi][nh * 2 + u] = __builtin_amdgcn_mfma_f32_16x16x32_bf16(
                        af[mi], bfr2[u], acc[mi][nh * 2 + u], 0, 0, 0);
            __builtin_amdgcn_s_setprio(0);
        };

        // phase 0: A kk0 + B kk0,nh0
        ldA(0); ldB(0, 0);
        if (pf) ISSUE2(kt1, nxt, 2);
        __builtin_amdgcn_s_barrier();
        asm volatile("s_waitcnt lgkmcnt(0)" ::: "memory");
        __builtin_amdgcn_sched_barrier(0);
        mm(0);
        __builtin_amdgcn_s_barrier();
        // phase 1: B kk0,nh1 (A-frags reused)
        ldB(0, 1);
        if (pf) ISSUE2(kt1, nxt, 4);
        __builtin_amdgcn_s_barrier();
        asm volatile("s_waitcnt lgkmcnt(0)" ::: "memory");
        __builtin_amdgcn_sched_barrier(0);
        mm(1);
        __builtin_amdgcn_s_barrier();
        // phase 2: A kk1 + B kk1,nh0
        ldA(1); ldB(1, 0);
        if (pf) ISSUE2(kt1, nxt, 6);
        __builtin_amdgcn_s_barrier();
        asm volatile("s_waitcnt lgkmcnt(0)" ::: "memory");
        __builtin_amdgcn_sched_barrier(0);
        mm(0);
        __builtin_amdgcn_s_barrier();
        // phase 3: B kk1,nh1
        ldB(1, 1);
        __builtin_amdgcn_s_barrier();
        asm volatile("s_waitcnt lgkmcnt(0)" ::: "memory");
        __builtin_amdgcn_sched_barrier(0);
        mm(1);
        __builtin_amdgcn_s_barrier();
    }

    // ---- epilogues ----
    if constexpr (MODE == 0) {
        ushort* Cp = (ushort*)Cptr_ + z * sC;
        #pragma unroll
        for (int mi = 0; mi < 8; ++mi) {
            const int row = m0 + wr * 128 + mi * 16 + g * 4;
            #pragma unroll
            for (int ni = 0; ni < 4; ++ni) {
                const int col = n0 + wcn * 64 + ni * 16 + c;
                const float bv = HAS_BIAS ? bias[col] : 0.f;
                ushort v[4];
                #pragma unroll
                for (int r = 0; r < 4; ++r) v[r] = f2bf(acc[mi][ni][r] + bv);
                #pragma unroll
                for (int r = 0; r < 4; ++r) Cp[(long)(row + r) * ldc + col] = v[r];
                if constexpr (WRITE_T) {
                    const int bb = row >> rbshift;
                    const int ii = row & ((1 << rbshift) - 1);
                    *(ushort4*)&CTptr_[(long)bb * sCT + (long)col * ldct + ii] =
                        make_ushort4(v[0], v[1], v[2], v[3]);
                }
            }
        }
    } else if constexpr (MODE == 1) {
        ushort* Ep  = (ushort*)Cptr_ + z * sC;
        ushort* ETp = CTptr_ + z * sCT;
        float* rs = rsum_ + z * sSum;
        float* cs = csum_ + z * sSum;
        float rowpart[8][4] = {};
        float colpart[4] = {};
        #pragma unroll
        for (int mi = 0; mi < 8; ++mi) {
            const int row = m0 + wr * 128 + mi * 16 + g * 4;
            #pragma unroll
            for (int ni = 0; ni < 4; ++ni) {
                const int col = n0 + wcn * 64 + ni * 16 + c;
                ushort v[4];
                #pragma unroll
                for (int r = 0; r < 4; ++r) {
                    const float s = acc[mi][ni][r];
                    const float t = 1.f - 2.f / (__expf(2.f * s) + 1.f);  // tanh(s)
                    const float e = __expf(t);
                    rowpart[mi][r] += e;
                    colpart[ni]    += e;
                    v[r] = f2bf(e);
                }
                #pragma unroll
                for (int r = 0; r < 4; ++r) Ep[(long)(row + r) * ldc + col] = v[r];
                *(ushort4*)&ETp[(long)col * ldct + row] = make_ushort4(v[0], v[1], v[2], v[3]);
            }
        }
        #pragma unroll
        for (int mi = 0; mi < 8; ++mi) {
            #pragma unroll
            for (int r = 0; r < 4; ++r) {
                float v = rowpart[mi][r];
                v += __shfl_xor(v, 1); v += __shfl_xor(v, 2);
                v += __shfl_xor(v, 4); v += __shfl_xor(v, 8);
                if (c == 0) atomicAdd(&rs[m0 + wr * 128 + mi * 16 + g * 4 + r], v);
            }
        }
        #pragma unroll
        for (int ni = 0; ni < 4; ++ni) {
            float v = colpart[ni];
            v += __shfl_xor(v, 16); v += __shfl_xor(v, 32);
            if (g == 0) atomicAdd(&cs[n0 + wcn * 64 + ni * 16 + c], v);
        }
    } else if constexpr (MODE == 2) {
        const float* sc = scale_ + z * sSum;
        ushort* Cp = (ushort*)Cptr_ + z * sC;
        #pragma unroll
        for (int mi = 0; mi < 8; ++mi) {
            const int row = m0 + wr * 128 + mi * 16 + g * 4;
            float rcp[4];
            #pragma unroll
            for (int r = 0; r < 4; ++r) rcp[r] = 1.f / sc[row + r];
            #pragma unroll
            for (int ni = 0; ni < 4; ++ni) {
                const int col = n0 + wcn * 64 + ni * 16 + c;
                #pragma unroll
                for (int r = 0; r < 4; ++r)
                    Cp[(long)(row + r) * ldc + col] = f2bf(acc[mi][ni][r] * rcp[r]);
            }
        }
    } else { // MODE == 3
        float* Co = (float*)Cptr_;
        #pragma unroll
        for (int mi = 0; mi < 8; ++mi) {
            const int row = m0 + wr * 128 + mi * 16 + g * 4;
            #pragma unroll
            for (int ni = 0; ni < 4; ++ni) {
                const int col = n0 + wcn * 64 + ni * 16 + c;
                const float bv = bias[col];
                #pragma unroll
                for (int r = 0; r < 4; ++r) {
                    const long idx = (long)(row + r) * ldc + col;
                    Co[idx] = acc[mi][ni][r] + bv + resid_[idx];
                }
            }
        }
    }
}

// f32 -> bf16 elementwise (vectorized 8/thread, grid-stride)
__global__ __launch_bounds__(256)
void cast32to16(const float* __restrict__ in, ushort* __restrict__ out, long n) {
    const long stride = (long)gridDim.x * 256 * 8;
    for (long i = ((long)blockIdx.x * 256 + threadIdx.x) * 8; i < n; i += stride) {
        const float4 f0 = *(const float4*)(in + i);
        const float4 f1 = *(const float4*)(in + i + 4);
        uint4 w;
        w.x = (uint)f2bf(f0.x) | ((uint)f2bf(f0.y) << 16);
        w.y = (uint)f2bf(f0.z) | ((uint)f2bf(f0.w) << 16);
        w.z = (uint)f2bf(f1.x) | ((uint)f2bf(f1.y) << 16);
        w.w = (uint)f2bf(f1.z) | ((uint)f2bf(f1.w) << 16);
        *(uint4*)(out + i) = w;
    }
}

// f32 [R][C] -> bf16 [C][R]
__global__ __launch_bounds__(256)
void tcast(const float* __restrict__ in, ushort* __restrict__ out, int R, int C) {
    __shared__ float t[32][33];
    const int bx = blockIdx.x * 32, by = blockIdx.y * 32;
    const int tx = threadIdx.x, ty = threadIdx.y; // (32, 8)
    for (int i = ty; i < 32; i += 8) {
        const int r = by + i, cc = bx + tx;
        if (r < R && cc < C) t[i][tx] = in[(long)r * C + cc];
    }
    __syncthreads();
    for (int i = ty; i < 32; i += 8) {
        const int cc = bx + i, r = by + tx;
        if (cc < C && r < R) out[(long)cc * R + r] = f2bf(t[tx][i]);
    }
}

// in-place LayerNorm, one row per block
template<int D>
__global__ __launch_bounds__(256)
void ln_rows(float* __restrict__ y, const float* __restrict__ gam, const float* __restrict__ bet) {
    constexpr int NV = D / 256;
    const long row = blockIdx.x;
    float* p = y + row * D;
    const int tid = threadIdx.x;
    float v[NV];
    float s = 0.f, s2 = 0.f;
    #pragma unroll
    for (int k = 0; k < NV; ++k) {
        v[k] = p[tid + k * 256];
        s += v[k]; s2 += v[k] * v[k];
    }
    #pragma unroll
    for (int off = 1; off < 64; off <<= 1) {
        s  += __shfl_xor(s, off);
        s2 += __shfl_xor(s2, off);
    }
    __shared__ float ws[4], ws2[4];
    const int wave = tid >> 6, lane = tid & 63;
    if (lane == 0) { ws[wave] = s; ws2[wave] = s2; }
    __syncthreads();
    s  = ws[0] + ws[1] + ws[2] + ws[3];
    s2 = ws2[0] + ws2[1] + ws2[2] + ws2[3];
    const float mu  = s / D;
    const float var = s2 / D - mu * mu;
    const float rstd = rsqrtf(var + 1e-5f);
    #pragma unroll
    for (int k = 0; k < NV; ++k) {
        const int i = tid + k * 256;
        p[i] = (v[k] - mu) * rstd * gam[i] + bet[i];
    }
}

extern "C" void kernel_launch(void* const* d_in, const int* in_sizes, int n_in,
                              void* d_out, int out_size, void* d_ws, size_t ws_size,
                              hipStream_t stream)
{
    (void)in_sizes; (void)n_in; (void)out_size; (void)ws_size;
    const float* z_a    = (const float*)d_in[0];
    const float* z_b    = (const float*)d_in[1];
    const float* Wa     = (const float*)d_in[2];
    const float* ba     = (const float*)d_in[3];
    const float* Wb     = (const float*)d_in[4];
    const float* bb     = (const float*)d_in[5];
    const float* Wco    = (const float*)d_in[6];
    const float* Woa    = (const float*)d_in[7];
    const float* boa    = (const float*)d_in[8];
    const float* Wob    = (const float*)d_in[9];
    const float* bob    = (const float*)d_in[10];
    const float* ga     = (const float*)d_in[11];
    const float* beta_a = (const float*)d_in[12];
    const float* gb     = (const float*)d_in[13];
    const float* beta_b = (const float*)d_in[14];

    const int Bn = 16, LA = 2048, LB = 2048, DA = 768, DB = 512, DH = 512;
    const long MA = (long)Bn * LA;
    const long MB = (long)Bn * LB;

    char* w = (char*)d_ws;
    size_t off = 0;
    auto alc = [&](size_t bytes) { void* p = w + off; off += (bytes + 255) & ~(size_t)255; return p; };

    ushort* WaT  = (ushort*)alc((size_t)DH * DA * 2);
    ushort* WbT  = (ushort*)alc((size_t)DH * DB * 2);
    ushort* WcoT = (ushort*)alc((size_t)DH * DH * 2);
    ushort* WoaT = (ushort*)alc((size_t)DA * DH * 2);
    ushort* WobT = (ushort*)alc((size_t)DB * DH * 2);
    ushort* h_a  = (ushort*)alc((size_t)MA * DH * 2);
    ushort* h_b  = (ushort*)alc((size_t)MB * DH * 2);
    ushort* h_aT = (ushort*)alc((size_t)Bn * DH * LA * 2);
    ushort* h_bT = (ushort*)alc((size_t)Bn * DH * LB * 2);
    ushort* Ma   = (ushort*)alc((size_t)MA * DH * 2);
    ushort* E    = (ushort*)alc((size_t)Bn * LA * LB * 2);
    ushort* ET   = (ushort*)alc((size_t)Bn * LB * LA * 2);
    ushort* Pa   = (ushort*)alc((size_t)MA * DH * 2);
    ushort* Pb   = (ushort*)alc((size_t)MB * DH * 2);
    float*  rsum = (float*)alc((size_t)Bn * LA * 4);
    float*  csum = (float*)alc((size_t)Bn * LB * 4);

    // bf16 copies of z_a, z_b aliased into E's region (dead before E is written)
    ushort* za16 = E;
    ushort* zb16 = E + (size_t)MA * DA;

    dim3 blk(512, 1, 1);
    dim3 blk256(256, 1, 1);
    dim3 tb(32, 8, 1);
    const int SHM = 2 * BUF_U * 2;   // 131072 B dynamic LDS

    // weight transposes (f32 -> bf16, [K][N] -> [N][K])
    tcast<<<dim3(DH / 32, DA / 32, 1), tb, 0, stream>>>(Wa,  WaT,  DA, DH);
    tcast<<<dim3(DH / 32, DB / 32, 1), tb, 0, stream>>>(Wb,  WbT,  DB, DH);
    tcast<<<dim3(DH / 32, DH / 32, 1), tb, 0, stream>>>(Wco, WcoT, DH, DH);
    tcast<<<dim3(DA / 32, DH / 32, 1), tb, 0, stream>>>(Woa, WoaT, DH, DA);
    tcast<<<dim3(DB / 32, DH / 32, 1), tb, 0, stream>>>(Wob, WobT, DH, DB);

    // activations f32 -> bf16
    cast32to16<<<dim3(2048, 1, 1), blk256, 0, stream>>>(z_a, za16, MA * DA);
    cast32to16<<<dim3(2048, 1, 1), blk256, 0, stream>>>(z_b, zb16, MB * DB);

    // zero softmax denominators (rsum & csum are contiguous)
    hipMemsetAsync(rsum, 0, (size_t)Bn * (LA + LB) * sizeof(float), stream);

    // h_a = z_a @ Wa + ba   (also writes h_aT per batch)
    gemm_bt<0, true, true><<<dim3(MA / BM, DH / BN, 1), blk, SHM, stream>>>(
        za16, WaT, h_a, h_aT, ba, nullptr, nullptr, nullptr, nullptr,
        (int)MA, DH, DA, DA, DA, DH, 0, 0, 0, (long)DH * LA, 0, LA, 11);

    // h_b = z_b @ Wb + bb   (also writes h_bT per batch)
    gemm_bt<0, true, true><<<dim3(MB / BM, DH / BN, 1), blk, SHM, stream>>>(
        zb16, WbT, h_b, h_bT, bb, nullptr, nullptr, nullptr, nullptr,
        (int)MB, DH, DB, DB, DB, DH, 0, 0, 0, (long)DH * LB, 0, LB, 11);

    // Ma = h_a @ W_co
    gemm_bt<0, false, false><<<dim3(MA / BM, DH / BN, 1), blk, SHM, stream>>>(
        h_a, WcoT, Ma, nullptr, nullptr, nullptr, nullptr, nullptr, nullptr,
        (int)MA, DH, DH, DH, DH, DH, 0, 0, 0, 0, 0, 0, 0);

    // scores: E = exp(tanh(Ma @ h_b^T)), E^T, rowsum, colsum  (batched)
    gemm_bt<1, false, false><<<dim3(LA / BM, LB / BN, Bn), blk, SHM, stream>>>(
        Ma, h_b, E, ET, nullptr, nullptr, rsum, csum, nullptr,
        LA, LB, DH, DH, DH, LB,
        (long)LA * DH, (long)LB * DH, (long)LA * LB, (long)LB * LA, LA, LA, 0);

    // Pa = (E @ h_b) / rowsum  (batched)
    gemm_bt<2, false, false><<<dim3(LA / BM, DH / BN, Bn), blk, SHM, stream>>>(
        E, h_bT, Pa, nullptr, nullptr, nullptr, nullptr, nullptr, rsum,
        LA, DH, LB, LB, LB, DH,
        (long)LA * LB, (long)DH * LB, (long)LA * DH, 0, LA, 0, 0);

    // Pb = (E^T @ h_a) / colsum  (batched)
    gemm_bt<2, false, false><<<dim3(LB / BM, DH / BN, Bn), blk, SHM, stream>>>(
        ET, h_aT, Pb, nullptr, nullptr, nullptr, nullptr, nullptr, csum,
        LB, DH, LA, LA, LA, DH,
        (long)LB * LA, (long)DH * LA, (long)LB * DH, 0, LB, 0, 0);

    float* outA = (float*)d_out;
    float* outB = outA + MA * DA;

    // z_a_pre = Pa @ Woa + boa + z_a  -> d_out (f32, in place for LN)
    gemm_bt<3, true, false><<<dim3(MA / BM, DA / BN, 1), blk, SHM, stream>>>(
        Pa, WoaT, outA, nullptr, boa, z_a, nullptr, nullptr, nullptr,
        (int)MA, DA, DH, DH, DH, DA, 0, 0, 0, 0, 0, 0, 0);

    // z_b_pre = Pb @ Wob + bob + z_b  -> d_out
    gemm_bt<3, true, false><<<dim3(MB / BM, DB / BN, 1), blk, SHM, stream>>>(
        Pb, WobT, outB, nullptr, bob, z_b, nullptr, nullptr, nullptr,
        (int)MB, DB, DH, DH, DH, DB, 0, 0, 0, 0, 0, 0, 0);

    // LayerNorms in place on d_out
    ln_rows<768><<<dim3((unsigned)MA, 1, 1), blk256, 0, stream>>>(outA, ga, beta_a);
    ln_rows<512><<<dim3((unsigned)MB, 1, 1), blk256, 0, stream>>>(outB, gb, beta_b);
}